// Round 12
// baseline (492.789 us; speedup 1.0000x reference)
//
#include <hip/hip_runtime.h>
#include <hip/hip_bf16.h>
#include <math.h>

#define HDIM 128
#define ICDIM 64
#define OCDIM 32
#define BN_EPS 1e-5f
#define NCH 64    // nodes per proj block
#define NCHG 128  // nodes per gemm4 block

typedef __attribute__((ext_vector_type(8))) short bv8;   // 8 x bf16 bits (4 VGPR)
typedef __attribute__((ext_vector_type(4))) float fv4;   // MFMA accumulator

static __device__ __forceinline__ unsigned short f2bf(float v) {
    __hip_bfloat16 t = __float2bfloat16(v);
    return *(unsigned short*)&t;
}
static __device__ __forceinline__ float bflo(unsigned int u) {
    union { unsigned int i; float f; } c; c.i = u << 16; return c.f;
}
static __device__ __forceinline__ float bfhi(unsigned int u) {
    union { unsigned int i; float f; } c; c.i = u & 0xffff0000u; return c.f;
}
static __device__ __forceinline__ unsigned int pack2bf(float a, float b) {
    return (unsigned int)f2bf(a) | ((unsigned int)f2bf(b) << 16);
}

// ---------------------------------------------------------------------------
// wprep: blocks 0..11: conv_w -> Wt [12][128o][128i] bf16; block 12: proj_w -> Wp
// ---------------------------------------------------------------------------
__global__ void wprep_kernel(const float* __restrict__ conv_w,
                             const float* __restrict__ proj_w,
                             __hip_bfloat16* __restrict__ Wt,
                             __hip_bfloat16* __restrict__ Wp) {
    int mat = blockIdx.x;
    if (mat < 12) {
        const float* s = conv_w + (size_t)mat * HDIM * HDIM;
        __hip_bfloat16* d = Wt + (size_t)mat * HDIM * HDIM;
        for (int idx = threadIdx.x; idx < HDIM * HDIM; idx += 256) {
            int i = idx >> 7, o = idx & 127;
            d[(size_t)o * HDIM + i] = __float2bfloat16(s[idx]);
        }
    } else {
        for (int idx = threadIdx.x; idx < ICDIM * HDIM; idx += 256) {
            int i = idx >> 7, o = idx & 127;
            Wp[(size_t)o * ICDIM + i] = __float2bfloat16(proj_w[idx]);
        }
    }
}

// ---------------------------------------------------------------------------
// proj_mfma: h = relu(x @ proj_w + proj_b) -> bf16 h   (xs XOR-swizzled)
// ---------------------------------------------------------------------------
__global__ __launch_bounds__(256)
void proj_mfma_kernel(const float* __restrict__ x,
                      const __hip_bfloat16* __restrict__ wp,  // [128o][64i]
                      const float* __restrict__ b,
                      __hip_bfloat16* __restrict__ h, int n) {
    __shared__ unsigned int xs[NCH * ICDIM / 2];   // 8 KB bf16, [node][64] swizzled
    int tid = threadIdx.x;
    int m0 = blockIdx.x * NCH;

    const float2* xsrc = (const float2*)(x + (size_t)m0 * ICDIM);
    for (int i = tid; i < NCH * ICDIM / 2; i += 256) {
        int node = m0 + (i >> 5);
        float2 v = (node < n) ? xsrc[i] : (float2){0.f, 0.f};
        xs[i ^ (((i >> 5) & 7) << 2)] = pack2bf(v.x, v.y);   // word-level swizzle
    }

    int wv = tid >> 6;          // 0..3  -> out-ch slice wv*32
    int lane = tid & 63;
    int j = lane & 15;          // node-in-tile
    int kg = lane >> 4;         // k-group
    int sw = (j & 7) << 4;      // read-side swizzle (row&7 == j&7)

    bv8 af[2][2];
#pragma unroll
    for (int gs = 0; gs < 2; ++gs)
#pragma unroll
        for (int ks = 0; ks < 2; ++ks)
            af[gs][ks] = *(const bv8*)((const unsigned short*)wp +
                (size_t)(wv * 32 + gs * 16 + j) * ICDIM + ks * 32 + kg * 8);

    float4 bias0 = *(const float4*)(b + wv * 32 + kg * 4);
    float4 bias1 = *(const float4*)(b + wv * 32 + 16 + kg * 4);

    __syncthreads();

#pragma unroll
    for (int t4 = 0; t4 < NCH / 16; ++t4) {
        const char* rowbase = (const char*)xs + (t4 * 16 + j) * (ICDIM * 2);
        fv4 acc0 = (fv4){0.f, 0.f, 0.f, 0.f};
        fv4 acc1 = (fv4){0.f, 0.f, 0.f, 0.f};
#pragma unroll
        for (int ks = 0; ks < 2; ++ks) {
            bv8 bf = *(const bv8*)(rowbase + ((kg * 16 + ks * 64) ^ sw));
            acc0 = __builtin_amdgcn_mfma_f32_16x16x32_bf16(af[0][ks], bf, acc0, 0, 0, 0);
            acc1 = __builtin_amdgcn_mfma_f32_16x16x32_bf16(af[1][ks], bf, acc1, 0, 0, 0);
        }
        int node = m0 + t4 * 16 + j;
        if (node < n) {
            unsigned short* o =
                (unsigned short*)h + (size_t)node * HDIM + wv * 32 + kg * 4;
            ushort4 r0, r1;
            r0.x = f2bf(fmaxf(acc0.x + bias0.x, 0.f));
            r0.y = f2bf(fmaxf(acc0.y + bias0.y, 0.f));
            r0.z = f2bf(fmaxf(acc0.z + bias0.z, 0.f));
            r0.w = f2bf(fmaxf(acc0.w + bias0.w, 0.f));
            r1.x = f2bf(fmaxf(acc1.x + bias1.x, 0.f));
            r1.y = f2bf(fmaxf(acc1.y + bias1.y, 0.f));
            r1.z = f2bf(fmaxf(acc1.z + bias1.z, 0.f));
            r1.w = f2bf(fmaxf(acc1.w + bias1.w, 0.f));
            *(ushort4*)o = r0;
            *(ushort4*)(o + 16) = r1;
        }
    }
}

// ---------------------------------------------------------------------------
// gemm4_fused: one block = 128 nodes x all 4 lins; 16 waves = 4 lins x 4 slices.
//   hs XOR-swizzled; per-wave weights in registers; 8 node-tiles inner.
// ---------------------------------------------------------------------------
__global__ __launch_bounds__(1024)
void gemm4_fused_kernel(const __hip_bfloat16* __restrict__ hB,
                        const float* __restrict__ Ssrc,       // null for layer 0
                        const float* __restrict__ stp,        // stats prev layer
                        const float* __restrict__ gma,
                        const float* __restrict__ bta,
                        const __hip_bfloat16* __restrict__ wt4, // [4][128o][128i]
                        const float* __restrict__ b4,           // [4][128]
                        __hip_bfloat16* __restrict__ K,
                        unsigned int* __restrict__ QV,          // [n][128] words
                        float* __restrict__ S, int n) {
    __shared__ unsigned short hs[NCHG * HDIM];   // 32 KB, swizzled
    int tid = threadIdx.x;
    int m0 = blockIdx.x * NCHG;

    if (Ssrc) {
        const float4* src = (const float4*)(Ssrc + (size_t)m0 * HDIM);
        float invn = 1.f / (float)n;
#pragma unroll
        for (int it = 0; it < 2; ++it) {
            int idx = it * 1024 + tid;
            float4 v0 = src[idx * 2];
            float4 v1 = src[idx * 2 + 1];
            int c0 = (idx * 8) & 127;
            float vv[8] = {v0.x, v0.y, v0.z, v0.w, v1.x, v1.y, v1.z, v1.w};
            int wsw = ((idx >> 4) & 7) << 4;
            unsigned int* dst = (unsigned int*)((char*)hs + ((idx * 16) ^ wsw));
#pragma unroll
            for (int p = 0; p < 8; p += 2) {
                int c = c0 + p;
                float mA = stp[c] * invn, mB = stp[c + 1] * invn;
                float scA = gma[c] * rsqrtf(stp[128 + c] * invn - mA * mA + BN_EPS);
                float scB = gma[c + 1] * rsqrtf(stp[129 + c] * invn - mB * mB + BN_EPS);
                float shA = bta[c] - mA * scA, shB = bta[c + 1] - mB * scB;
                float rA = fmaxf(fmaf(vv[p], scA, shA), 0.f);
                float rB = fmaxf(fmaf(vv[p + 1], scB, shB), 0.f);
                dst[p >> 1] = pack2bf(rA, rB);
            }
        }
    } else {
        const uint4* src = (const uint4*)((const unsigned short*)hB + (size_t)m0 * HDIM);
#pragma unroll
        for (int it = 0; it < 2; ++it) {
            int idx = it * 1024 + tid;
            int wsw = ((idx >> 4) & 7) << 4;
            *(uint4*)((char*)hs + ((idx * 16) ^ wsw)) = src[idx];
        }
    }

    int wv = tid >> 6;          // 0..15
    int lane = tid & 63;
    int lin = wv >> 2;          // 0..3
    int g2 = wv & 3;            // out-channel slice: channels g2*32 .. +31
    int j = lane & 15;          // node-in-tile (B col, D col)
    int kg = lane >> 4;         // k-group
    int sw = (j & 7) << 4;      // read-side swizzle (row&7 == j&7)

    const unsigned short* wbase =
        (const unsigned short*)(wt4 + (size_t)lin * HDIM * HDIM);
    bv8 af[2][4];
#pragma unroll
    for (int gs = 0; gs < 2; ++gs)
#pragma unroll
        for (int ks = 0; ks < 4; ++ks)
            af[gs][ks] = *(const bv8*)(wbase +
                (size_t)(g2 * 32 + gs * 16 + j) * HDIM + ks * 32 + kg * 8);

    const float* bl = b4 + lin * HDIM;
    float4 bias0 = *(const float4*)(bl + g2 * 32 + kg * 4);
    float4 bias1 = *(const float4*)(bl + g2 * 32 + 16 + kg * 4);

    __syncthreads();

#pragma unroll
    for (int t4 = 0; t4 < NCHG / 16; ++t4) {
        const char* rowbase = (const char*)hs + (t4 * 16 + j) * (HDIM * 2);
        fv4 acc0 = (fv4){0.f, 0.f, 0.f, 0.f};
        fv4 acc1 = (fv4){0.f, 0.f, 0.f, 0.f};
#pragma unroll
        for (int ks = 0; ks < 4; ++ks) {
            bv8 bf = *(const bv8*)(rowbase + ((kg * 16 + ks * 64) ^ sw));
            acc0 = __builtin_amdgcn_mfma_f32_16x16x32_bf16(af[0][ks], bf, acc0, 0, 0, 0);
            acc1 = __builtin_amdgcn_mfma_f32_16x16x32_bf16(af[1][ks], bf, acc1, 0, 0, 0);
        }
        int node = m0 + t4 * 16 + j;
        if (node >= n) continue;
        int c0 = g2 * 32 + kg * 4;
        float f0 = acc0.x + bias0.x, f1 = acc0.y + bias0.y;
        float f2 = acc0.z + bias0.z, f3 = acc0.w + bias0.w;
        float f4 = acc1.x + bias1.x, f5 = acc1.y + bias1.y;
        float f6 = acc1.z + bias1.z, f7 = acc1.w + bias1.w;
        if (lin == 3) {
            float* o = S + (size_t)node * HDIM + c0;
            *(float4*)o = (float4){f0, f1, f2, f3};
            *(float4*)(o + 16) = (float4){f4, f5, f6, f7};
        } else if (lin == 0) {
            unsigned short* o = (unsigned short*)K + (size_t)node * HDIM + c0;
            *(ushort4*)o = (ushort4){f2bf(f0), f2bf(f1), f2bf(f2), f2bf(f3)};
            *(ushort4*)(o + 16) = (ushort4){f2bf(f4), f2bf(f5), f2bf(f6), f2bf(f7)};
        } else {
            // 8B-granular QV: chunk c0/4 at ushort 2*c0; q at +0, v at +4
            unsigned short* o = (unsigned short*)QV + (size_t)node * 256 + 2 * c0
                              + ((lin == 2) ? 4 : 0);
            *(ushort4*)o = (ushort4){f2bf(f0), f2bf(f1), f2bf(f2), f2bf(f3)};
            *(ushort4*)(o + 32) = (ushort4){f2bf(f4), f2bf(f5), f2bf(f6), f2bf(f7)};
        }
    }
}

// ---------------------------------------------------------------------------
// counting sort of edges by dst: hist -> scan1 -> scan23 -> scatter
// ---------------------------------------------------------------------------
__global__ void hist_kernel(const int* __restrict__ ei, int* __restrict__ deg, int e) {
    int i = blockIdx.x * 256 + threadIdx.x;
    if (i < e) atomicAdd(&deg[ei[(size_t)e + i]], 1);
}

__global__ void scan1_kernel(const int* __restrict__ deg, int* __restrict__ incl,
                             int* __restrict__ bsum, int n) {
    __shared__ int tmp[256];
    int i = blockIdx.x * 256 + threadIdx.x;
    int v = (i < n) ? deg[i] : 0;
    tmp[threadIdx.x] = v;
    __syncthreads();
    for (int ofs = 1; ofs < 256; ofs <<= 1) {
        int t = (threadIdx.x >= ofs) ? tmp[threadIdx.x - ofs] : 0;
        __syncthreads();
        tmp[threadIdx.x] += t;
        __syncthreads();
    }
    if (i < n) incl[i] = tmp[threadIdx.x];
    if (threadIdx.x == 255) bsum[blockIdx.x] = tmp[255];
}

__global__ void scan23_kernel(const int* __restrict__ deg, const int* __restrict__ incl,
                              const int* __restrict__ bsum, int* __restrict__ off,
                              int* __restrict__ cursor, int n, int e, int nb) {
    __shared__ int tmp[256];
    int t = threadIdx.x;
    tmp[t] = (t < nb) ? bsum[t] : 0;
    __syncthreads();
    for (int ofs = 1; ofs < 256; ofs <<= 1) {
        int a = (t >= ofs) ? tmp[t - ofs] : 0;
        __syncthreads();
        tmp[t] += a;
        __syncthreads();
    }
    int pre = (blockIdx.x == 0) ? 0 : tmp[blockIdx.x - 1];
    int i = blockIdx.x * 256 + t;
    if (i < n) {
        int ex = incl[i] - deg[i] + pre;
        off[i] = ex;
        cursor[i] = ex;
        if (i == n - 1) off[n] = e;
    }
}

__global__ void scatter_kernel(const int* __restrict__ ei, int* __restrict__ cursor,
                               int* __restrict__ esrc, int e) {
    int i = blockIdx.x * 256 + threadIdx.x;
    if (i < e) {
        int dst = ei[(size_t)e + i];
        int pos = atomicAdd(&cursor[dst], 1);
        esrc[pos] = ei[i];
    }
}

// ---------------------------------------------------------------------------
// agg + fused stats: grid-stride over dsts (wave per dst); per-lane channel-
// sticky sum/sumsq accumulators; block LDS reduce -> 256 atomicAdds.
// ---------------------------------------------------------------------------
__global__ __launch_bounds__(256)
void agg_kernel(const int* __restrict__ off, const int* __restrict__ esrc,
                const __hip_bfloat16* __restrict__ kb,
                const unsigned int* __restrict__ QV,
                float* __restrict__ S, float* __restrict__ stats, int n) {
    int wv = threadIdx.x >> 6;
    int lane = threadIdx.x & 63;
    int half = lane >> 5;       // edge parity within the pair
    int cl = lane & 31;         // 4-channel chunk index
    const char* qvb = (const char*)QV;

    float ss0 = 0.f, ss1 = 0.f, ss2 = 0.f, ss3 = 0.f;
    float sq0 = 0.f, sq1 = 0.f, sq2 = 0.f, sq3 = 0.f;

#define EDGE4(u)                                                     \
    {                                                                \
        float g0 = k0 + bflo(u.x), g1 = k1 + bfhi(u.x);              \
        float g2 = k2 + bflo(u.y), g3 = k3 + bfhi(u.y);              \
        a0 += __fdividef(bflo(u.z), 1.f + __expf(-g0));              \
        a1 += __fdividef(bfhi(u.z), 1.f + __expf(-g1));              \
        a2 += __fdividef(bflo(u.w), 1.f + __expf(-g2));              \
        a3 += __fdividef(bfhi(u.w), 1.f + __expf(-g3));              \
    }

    for (int d = blockIdx.x * 4 + wv; d < n; d += gridDim.x * 4) {
        uint2 ku = *(const uint2*)((const unsigned short*)kb + (size_t)d * HDIM + 4 * cl);
        float k0 = bflo(ku.x), k1 = bfhi(ku.x), k2 = bflo(ku.y), k3 = bfhi(ku.y);
        float a0 = 0.f, a1 = 0.f, a2 = 0.f, a3 = 0.f;

        int j = off[d] + half, s1 = off[d + 1];
        for (; j + 2 < s1; j += 4) {
            int sA = esrc[j], sB = esrc[j + 2];
            uint4 uA = *(const uint4*)(qvb + (size_t)sA * 512 + cl * 16);
            uint4 uB = *(const uint4*)(qvb + (size_t)sB * 512 + cl * 16);
            EDGE4(uA);
            EDGE4(uB);
        }
        if (j < s1) {
            int sA = esrc[j];
            uint4 uA = *(const uint4*)(qvb + (size_t)sA * 512 + cl * 16);
            EDGE4(uA);
        }

        a0 += __shfl_xor(a0, 32);
        a1 += __shfl_xor(a1, 32);
        a2 += __shfl_xor(a2, 32);
        a3 += __shfl_xor(a3, 32);
        if (half == 0) {
            float4* sp = (float4*)(S + (size_t)d * HDIM) + cl;
            float4 o = *sp;
            o.x += a0; o.y += a1; o.z += a2; o.w += a3;
            *sp = o;
            ss0 += o.x; sq0 = fmaf(o.x, o.x, sq0);
            ss1 += o.y; sq1 = fmaf(o.y, o.y, sq1);
            ss2 += o.z; sq2 = fmaf(o.z, o.z, sq2);
            ss3 += o.w; sq3 = fmaf(o.w, o.w, sq3);
        }
    }
#undef EDGE4

    __shared__ float red[4][256];
    if (half == 0) {
        red[wv][cl * 4 + 0] = ss0;
        red[wv][cl * 4 + 1] = ss1;
        red[wv][cl * 4 + 2] = ss2;
        red[wv][cl * 4 + 3] = ss3;
        red[wv][128 + cl * 4 + 0] = sq0;
        red[wv][128 + cl * 4 + 1] = sq1;
        red[wv][128 + cl * 4 + 2] = sq2;
        red[wv][128 + cl * 4 + 3] = sq3;
    }
    __syncthreads();
    int t = threadIdx.x;
    float v = red[0][t] + red[1][t] + red[2][t] + red[3][t];
    atomicAdd(&stats[t], v);
}

// ---------------------------------------------------------------------------
// head_bn: out = relu(bn(S)) @ head_w + head_b
// ---------------------------------------------------------------------------
__global__ void head_bn_kernel(const float* __restrict__ S,
                               const float* __restrict__ stats,
                               const float* __restrict__ gamma,
                               const float* __restrict__ beta,
                               const float* __restrict__ w,
                               const float* __restrict__ b,
                               float* __restrict__ out, int n) {
    __shared__ float hsm[8][HDIM];
    float invn = 1.f / (float)n;
    for (int i = threadIdx.x; i < 8 * HDIM; i += 256) {
        int r = i >> 7, c = i & 127;
        int node = blockIdx.x * 8 + r;
        float v = 0.f;
        if (node < n) {
            float mean = stats[c] * invn;
            float var = stats[128 + c] * invn - mean * mean;
            float sc = gamma[c] * rsqrtf(var + BN_EPS);
            float sh = beta[c] - mean * sc;
            v = fmaxf(fmaf(S[(size_t)node * HDIM + c], sc, sh), 0.f);
        }
        hsm[r][c] = v;
    }
    __syncthreads();
    int c = threadIdx.x & 31;
    int ng = threadIdx.x >> 5;
    int node = blockIdx.x * 8 + ng;
    if (node >= n) return;
    float acc = b[c];
#pragma unroll
    for (int k = 0; k < HDIM; ++k)
        acc = fmaf(hsm[ng][k], w[k * OCDIM + c], acc);
    out[(size_t)node * OCDIM + c] = acc;
}

// ---------------------------------------------------------------------------
extern "C" void kernel_launch(void* const* d_in, const int* in_sizes, int n_in,
                              void* d_out, int out_size, void* d_ws, size_t ws_size,
                              hipStream_t stream) {
    const float* x      = (const float*)d_in[0];
    const int*   ei     = (const int*)  d_in[1];
    const float* proj_w = (const float*)d_in[2];
    const float* proj_b = (const float*)d_in[3];
    const float* conv_w = (const float*)d_in[4];  // [3][4][128][128]
    const float* conv_b = (const float*)d_in[5];  // [3][4][128]
    const float* bn_g   = (const float*)d_in[6];
    const float* bn_b   = (const float*)d_in[7];
    const float* head_w = (const float*)d_in[8];
    const float* head_b = (const float*)d_in[9];
    float* out = (float*)d_out;

    int n = in_sizes[0] / ICDIM;   // 50000
    int e = in_sizes[1] / 2;       // 600000

    size_t nh = (size_t)n * HDIM;
    // S f32 | st[768] | h bf16 | K bf16 | QV u32 | Wt | Wp | ints
    size_t need = nh * 4 + 768 * 4 + nh * 2 + nh * 2 + nh * 4
                + (size_t)12 * HDIM * HDIM * 2 + (size_t)HDIM * ICDIM * 2
                + ((size_t)3 * n + (n + 1) + 256 + e) * 4;
    if (ws_size < need) return;

    float* S  = (float*)d_ws;
    float* st = S + nh;                         // 3 x (sum[128], sumsq[128])
    __hip_bfloat16* h = (__hip_bfloat16*)(st + 768);
    __hip_bfloat16* K = h + nh;
    unsigned int* QV = (unsigned int*)(K + nh); // [n][128] words (8B interleave)
    __hip_bfloat16* Wt = (__hip_bfloat16*)(QV + nh);     // [3][4][128o][128i]
    __hip_bfloat16* Wp = Wt + (size_t)12 * HDIM * HDIM;  // [128o][64i]

    int* deg    = (int*)(Wp + (size_t)HDIM * ICDIM);
    int* incl   = deg + n;
    int* off    = incl + n;                     // n+1
    int* cursor = off + n + 1;
    int* bsum   = cursor + n;                   // 256
    int* esrc   = bsum + 256;                   // e

    hipMemsetAsync(st, 0, 768 * sizeof(float), stream);
    hipMemsetAsync(deg, 0, (size_t)n * sizeof(int), stream);

    int gb_e = (e + 255) / 256;
    int gb_n = (n + 255) / 256;   // 196 <= 256

    wprep_kernel<<<13, 256, 0, stream>>>(conv_w, proj_w, Wt, Wp);
    proj_mfma_kernel<<<(n + NCH - 1) / NCH, 256, 0, stream>>>(x, Wp, proj_b, h, n);

    hist_kernel<<<gb_e, 256, 0, stream>>>(ei, deg, e);
    scan1_kernel<<<gb_n, 256, 0, stream>>>(deg, incl, bsum, n);
    scan23_kernel<<<gb_n, 256, 0, stream>>>(deg, incl, bsum, off, cursor, n, e, gb_n);
    scatter_kernel<<<gb_e, 256, 0, stream>>>(ei, cursor, esrc, e);

    int gm = (n + NCHG - 1) / NCHG;
    for (int l = 0; l < 3; ++l) {
        const float* Ssrc = (l == 0) ? nullptr : S;
        const float* stp  = (l == 0) ? st : st + (size_t)(l - 1) * 256;
        const float* gma  = (l == 0) ? bn_g : bn_g + (size_t)(l - 1) * HDIM;
        const float* bta  = (l == 0) ? bn_b : bn_b + (size_t)(l - 1) * HDIM;
        gemm4_fused_kernel<<<gm, 1024, 0, stream>>>(
            h, Ssrc, stp, gma, bta,
            Wt + (size_t)l * 4 * HDIM * HDIM, conv_b + (size_t)l * 4 * HDIM,
            K, QV, S, n);
        agg_kernel<<<2048, 256, 0, stream>>>(off, esrc, K, QV, S, st + l * 256, n);
    }

    head_bn_kernel<<<(n + 7) / 8, 256, 0, stream>>>(
        S, st + 2 * 256, bn_g + 2 * HDIM, bn_b + 2 * HDIM, head_w, head_b, out, n);
}

// Round 13
// 465.851 us; speedup vs baseline: 1.0578x; 1.0578x over previous
//
#include <hip/hip_runtime.h>
#include <hip/hip_bf16.h>
#include <math.h>

#define HDIM 128
#define ICDIM 64
#define OCDIM 32
#define BN_EPS 1e-5f
#define NCH 64    // nodes per proj block
#define NCHG 128  // nodes per gemm4 block

typedef __attribute__((ext_vector_type(8))) short bv8;   // 8 x bf16 bits (4 VGPR)
typedef __attribute__((ext_vector_type(4))) float fv4;   // MFMA accumulator

static __device__ __forceinline__ unsigned short f2bf(float v) {
    __hip_bfloat16 t = __float2bfloat16(v);
    return *(unsigned short*)&t;
}
static __device__ __forceinline__ float bflo(unsigned int u) {
    union { unsigned int i; float f; } c; c.i = u << 16; return c.f;
}
static __device__ __forceinline__ float bfhi(unsigned int u) {
    union { unsigned int i; float f; } c; c.i = u & 0xffff0000u; return c.f;
}
static __device__ __forceinline__ unsigned int pack2bf(float a, float b) {
    return (unsigned int)f2bf(a) | ((unsigned int)f2bf(b) << 16);
}

// ---------------------------------------------------------------------------
// wprep: blocks 0..11: conv_w -> Wt [12][128o][128i] bf16; block 12: proj_w -> Wp
// ---------------------------------------------------------------------------
__global__ void wprep_kernel(const float* __restrict__ conv_w,
                             const float* __restrict__ proj_w,
                             __hip_bfloat16* __restrict__ Wt,
                             __hip_bfloat16* __restrict__ Wp) {
    int mat = blockIdx.x;
    if (mat < 12) {
        const float* s = conv_w + (size_t)mat * HDIM * HDIM;
        __hip_bfloat16* d = Wt + (size_t)mat * HDIM * HDIM;
        for (int idx = threadIdx.x; idx < HDIM * HDIM; idx += 256) {
            int i = idx >> 7, o = idx & 127;
            d[(size_t)o * HDIM + i] = __float2bfloat16(s[idx]);
        }
    } else {
        for (int idx = threadIdx.x; idx < ICDIM * HDIM; idx += 256) {
            int i = idx >> 7, o = idx & 127;
            Wp[(size_t)o * ICDIM + i] = __float2bfloat16(proj_w[idx]);
        }
    }
}

// ---------------------------------------------------------------------------
// proj_mfma: h = relu(x @ proj_w + proj_b) -> bf16 h   (xs XOR-swizzled)
// ---------------------------------------------------------------------------
__global__ __launch_bounds__(256)
void proj_mfma_kernel(const float* __restrict__ x,
                      const __hip_bfloat16* __restrict__ wp,  // [128o][64i]
                      const float* __restrict__ b,
                      __hip_bfloat16* __restrict__ h, int n) {
    __shared__ unsigned int xs[NCH * ICDIM / 2];   // 8 KB bf16, [node][64] swizzled
    int tid = threadIdx.x;
    int m0 = blockIdx.x * NCH;

    const float2* xsrc = (const float2*)(x + (size_t)m0 * ICDIM);
    for (int i = tid; i < NCH * ICDIM / 2; i += 256) {
        int node = m0 + (i >> 5);
        float2 v = (node < n) ? xsrc[i] : (float2){0.f, 0.f};
        xs[i ^ (((i >> 5) & 7) << 2)] = pack2bf(v.x, v.y);   // word-level swizzle
    }

    int wv = tid >> 6;          // 0..3  -> out-ch slice wv*32
    int lane = tid & 63;
    int j = lane & 15;          // node-in-tile
    int kg = lane >> 4;         // k-group
    int sw = (j & 7) << 4;      // read-side swizzle (row&7 == j&7)

    bv8 af[2][2];
#pragma unroll
    for (int gs = 0; gs < 2; ++gs)
#pragma unroll
        for (int ks = 0; ks < 2; ++ks)
            af[gs][ks] = *(const bv8*)((const unsigned short*)wp +
                (size_t)(wv * 32 + gs * 16 + j) * ICDIM + ks * 32 + kg * 8);

    float4 bias0 = *(const float4*)(b + wv * 32 + kg * 4);
    float4 bias1 = *(const float4*)(b + wv * 32 + 16 + kg * 4);

    __syncthreads();

#pragma unroll
    for (int t4 = 0; t4 < NCH / 16; ++t4) {
        const char* rowbase = (const char*)xs + (t4 * 16 + j) * (ICDIM * 2);
        fv4 acc0 = (fv4){0.f, 0.f, 0.f, 0.f};
        fv4 acc1 = (fv4){0.f, 0.f, 0.f, 0.f};
#pragma unroll
        for (int ks = 0; ks < 2; ++ks) {
            bv8 bf = *(const bv8*)(rowbase + ((kg * 16 + ks * 64) ^ sw));
            acc0 = __builtin_amdgcn_mfma_f32_16x16x32_bf16(af[0][ks], bf, acc0, 0, 0, 0);
            acc1 = __builtin_amdgcn_mfma_f32_16x16x32_bf16(af[1][ks], bf, acc1, 0, 0, 0);
        }
        int node = m0 + t4 * 16 + j;
        if (node < n) {
            unsigned short* o =
                (unsigned short*)h + (size_t)node * HDIM + wv * 32 + kg * 4;
            ushort4 r0, r1;
            r0.x = f2bf(fmaxf(acc0.x + bias0.x, 0.f));
            r0.y = f2bf(fmaxf(acc0.y + bias0.y, 0.f));
            r0.z = f2bf(fmaxf(acc0.z + bias0.z, 0.f));
            r0.w = f2bf(fmaxf(acc0.w + bias0.w, 0.f));
            r1.x = f2bf(fmaxf(acc1.x + bias1.x, 0.f));
            r1.y = f2bf(fmaxf(acc1.y + bias1.y, 0.f));
            r1.z = f2bf(fmaxf(acc1.z + bias1.z, 0.f));
            r1.w = f2bf(fmaxf(acc1.w + bias1.w, 0.f));
            *(ushort4*)o = r0;
            *(ushort4*)(o + 16) = r1;
        }
    }
}

// ---------------------------------------------------------------------------
// gemm4_fused: one block = 128 nodes x all 4 lins; 16 waves = 4 lins x 4 slices.
//   hs XOR-swizzled; per-wave weights in registers; 8 node-tiles inner.
// ---------------------------------------------------------------------------
__global__ __launch_bounds__(1024)
void gemm4_fused_kernel(const __hip_bfloat16* __restrict__ hB,
                        const float* __restrict__ Ssrc,       // null for layer 0
                        const float* __restrict__ stp,        // stats prev layer
                        const float* __restrict__ gma,
                        const float* __restrict__ bta,
                        const __hip_bfloat16* __restrict__ wt4, // [4][128o][128i]
                        const float* __restrict__ b4,           // [4][128]
                        __hip_bfloat16* __restrict__ K,
                        unsigned int* __restrict__ QV,          // [n][128] words
                        float* __restrict__ S, int n) {
    __shared__ unsigned short hs[NCHG * HDIM];   // 32 KB, swizzled
    int tid = threadIdx.x;
    int m0 = blockIdx.x * NCHG;

    if (Ssrc) {
        const float4* src = (const float4*)(Ssrc + (size_t)m0 * HDIM);
        float invn = 1.f / (float)n;
#pragma unroll
        for (int it = 0; it < 2; ++it) {
            int idx = it * 1024 + tid;
            float4 v0 = src[idx * 2];
            float4 v1 = src[idx * 2 + 1];
            int c0 = (idx * 8) & 127;
            float vv[8] = {v0.x, v0.y, v0.z, v0.w, v1.x, v1.y, v1.z, v1.w};
            int wsw = ((idx >> 4) & 7) << 4;
            unsigned int* dst = (unsigned int*)((char*)hs + ((idx * 16) ^ wsw));
#pragma unroll
            for (int p = 0; p < 8; p += 2) {
                int c = c0 + p;
                float mA = stp[c] * invn, mB = stp[c + 1] * invn;
                float scA = gma[c] * rsqrtf(stp[128 + c] * invn - mA * mA + BN_EPS);
                float scB = gma[c + 1] * rsqrtf(stp[129 + c] * invn - mB * mB + BN_EPS);
                float shA = bta[c] - mA * scA, shB = bta[c + 1] - mB * scB;
                float rA = fmaxf(fmaf(vv[p], scA, shA), 0.f);
                float rB = fmaxf(fmaf(vv[p + 1], scB, shB), 0.f);
                dst[p >> 1] = pack2bf(rA, rB);
            }
        }
    } else {
        const uint4* src = (const uint4*)((const unsigned short*)hB + (size_t)m0 * HDIM);
#pragma unroll
        for (int it = 0; it < 2; ++it) {
            int idx = it * 1024 + tid;
            int wsw = ((idx >> 4) & 7) << 4;
            *(uint4*)((char*)hs + ((idx * 16) ^ wsw)) = src[idx];
        }
    }

    int wv = tid >> 6;          // 0..15
    int lane = tid & 63;
    int lin = wv >> 2;          // 0..3
    int g2 = wv & 3;            // out-channel slice: channels g2*32 .. +31
    int j = lane & 15;          // node-in-tile (B col, D col)
    int kg = lane >> 4;         // k-group
    int sw = (j & 7) << 4;      // read-side swizzle (row&7 == j&7)

    const unsigned short* wbase =
        (const unsigned short*)(wt4 + (size_t)lin * HDIM * HDIM);
    bv8 af[2][4];
#pragma unroll
    for (int gs = 0; gs < 2; ++gs)
#pragma unroll
        for (int ks = 0; ks < 4; ++ks)
            af[gs][ks] = *(const bv8*)(wbase +
                (size_t)(g2 * 32 + gs * 16 + j) * HDIM + ks * 32 + kg * 8);

    const float* bl = b4 + lin * HDIM;
    float4 bias0 = *(const float4*)(bl + g2 * 32 + kg * 4);
    float4 bias1 = *(const float4*)(bl + g2 * 32 + 16 + kg * 4);

    __syncthreads();

#pragma unroll
    for (int t4 = 0; t4 < NCHG / 16; ++t4) {
        const char* rowbase = (const char*)hs + (t4 * 16 + j) * (HDIM * 2);
        fv4 acc0 = (fv4){0.f, 0.f, 0.f, 0.f};
        fv4 acc1 = (fv4){0.f, 0.f, 0.f, 0.f};
#pragma unroll
        for (int ks = 0; ks < 4; ++ks) {
            bv8 bf = *(const bv8*)(rowbase + ((kg * 16 + ks * 64) ^ sw));
            acc0 = __builtin_amdgcn_mfma_f32_16x16x32_bf16(af[0][ks], bf, acc0, 0, 0, 0);
            acc1 = __builtin_amdgcn_mfma_f32_16x16x32_bf16(af[1][ks], bf, acc1, 0, 0, 0);
        }
        int node = m0 + t4 * 16 + j;
        if (node >= n) continue;
        int c0 = g2 * 32 + kg * 4;
        float f0 = acc0.x + bias0.x, f1 = acc0.y + bias0.y;
        float f2 = acc0.z + bias0.z, f3 = acc0.w + bias0.w;
        float f4 = acc1.x + bias1.x, f5 = acc1.y + bias1.y;
        float f6 = acc1.z + bias1.z, f7 = acc1.w + bias1.w;
        if (lin == 3) {
            float* o = S + (size_t)node * HDIM + c0;
            *(float4*)o = (float4){f0, f1, f2, f3};
            *(float4*)(o + 16) = (float4){f4, f5, f6, f7};
        } else if (lin == 0) {
            unsigned short* o = (unsigned short*)K + (size_t)node * HDIM + c0;
            *(ushort4*)o = (ushort4){f2bf(f0), f2bf(f1), f2bf(f2), f2bf(f3)};
            *(ushort4*)(o + 16) = (ushort4){f2bf(f4), f2bf(f5), f2bf(f6), f2bf(f7)};
        } else {
            // 8B-granular QV: chunk c0/4 at ushort 2*c0; q at +0, v at +4
            unsigned short* o = (unsigned short*)QV + (size_t)node * 256 + 2 * c0
                              + ((lin == 2) ? 4 : 0);
            *(ushort4*)o = (ushort4){f2bf(f0), f2bf(f1), f2bf(f2), f2bf(f3)};
            *(ushort4*)(o + 32) = (ushort4){f2bf(f4), f2bf(f5), f2bf(f6), f2bf(f7)};
        }
    }
}

// ---------------------------------------------------------------------------
// counting sort of edges by dst: hist -> scan1 -> scan23 -> scatter
// ---------------------------------------------------------------------------
__global__ void hist_kernel(const int* __restrict__ ei, int* __restrict__ deg, int e) {
    int i = blockIdx.x * 256 + threadIdx.x;
    if (i < e) atomicAdd(&deg[ei[(size_t)e + i]], 1);
}

__global__ void scan1_kernel(const int* __restrict__ deg, int* __restrict__ incl,
                             int* __restrict__ bsum, int n) {
    __shared__ int tmp[256];
    int i = blockIdx.x * 256 + threadIdx.x;
    int v = (i < n) ? deg[i] : 0;
    tmp[threadIdx.x] = v;
    __syncthreads();
    for (int ofs = 1; ofs < 256; ofs <<= 1) {
        int t = (threadIdx.x >= ofs) ? tmp[threadIdx.x - ofs] : 0;
        __syncthreads();
        tmp[threadIdx.x] += t;
        __syncthreads();
    }
    if (i < n) incl[i] = tmp[threadIdx.x];
    if (threadIdx.x == 255) bsum[blockIdx.x] = tmp[255];
}

__global__ void scan23_kernel(const int* __restrict__ deg, const int* __restrict__ incl,
                              const int* __restrict__ bsum, int* __restrict__ off,
                              int* __restrict__ cursor, int n, int e, int nb) {
    __shared__ int tmp[256];
    int t = threadIdx.x;
    tmp[t] = (t < nb) ? bsum[t] : 0;
    __syncthreads();
    for (int ofs = 1; ofs < 256; ofs <<= 1) {
        int a = (t >= ofs) ? tmp[t - ofs] : 0;
        __syncthreads();
        tmp[t] += a;
        __syncthreads();
    }
    int pre = (blockIdx.x == 0) ? 0 : tmp[blockIdx.x - 1];
    int i = blockIdx.x * 256 + t;
    if (i < n) {
        int ex = incl[i] - deg[i] + pre;
        off[i] = ex;
        cursor[i] = ex;
        if (i == n - 1) off[n] = e;
    }
}

__global__ void scatter_kernel(const int* __restrict__ ei, int* __restrict__ cursor,
                               int* __restrict__ esrc, int e) {
    int i = blockIdx.x * 256 + threadIdx.x;
    if (i < e) {
        int dst = ei[(size_t)e + i];
        int pos = atomicAdd(&cursor[dst], 1);
        esrc[pos] = ei[i];
    }
}

// ---------------------------------------------------------------------------
// agg: S[d] += sum_{j in seg(d)} sigmoid(k[d] + q[src_j]) * v[src_j]
// one wave per dst; lane = (edge-parity, 4-ch chunk); one uint4 gather
// serves 2 edges; halves combined via shfl_xor(32).  (R11 form, VGPR 32)
// ---------------------------------------------------------------------------
__global__ void agg_kernel(const int* __restrict__ off, const int* __restrict__ esrc,
                           const __hip_bfloat16* __restrict__ kb,
                           const unsigned int* __restrict__ QV,
                           float* __restrict__ S, int n) {
    int d = blockIdx.x * 4 + (threadIdx.x >> 6);
    if (d >= n) return;
    int lane = threadIdx.x & 63;
    int half = lane >> 5;       // edge parity within the pair
    int cl = lane & 31;         // 4-channel chunk index
    const char* qvb = (const char*)QV;

    uint2 ku = *(const uint2*)((const unsigned short*)kb + (size_t)d * HDIM + 4 * cl);
    float k0 = bflo(ku.x), k1 = bfhi(ku.x), k2 = bflo(ku.y), k3 = bfhi(ku.y);
    float a0 = 0.f, a1 = 0.f, a2 = 0.f, a3 = 0.f;

#define EDGE4(u)                                                     \
    {                                                                \
        float g0 = k0 + bflo(u.x), g1 = k1 + bfhi(u.x);              \
        float g2 = k2 + bflo(u.y), g3 = k3 + bfhi(u.y);              \
        a0 += __fdividef(bflo(u.z), 1.f + __expf(-g0));              \
        a1 += __fdividef(bfhi(u.z), 1.f + __expf(-g1));              \
        a2 += __fdividef(bflo(u.w), 1.f + __expf(-g2));              \
        a3 += __fdividef(bfhi(u.w), 1.f + __expf(-g3));              \
    }

    int j = off[d] + half, s1 = off[d + 1];
    for (; j + 2 < s1; j += 4) {
        int sA = esrc[j], sB = esrc[j + 2];
        uint4 uA = *(const uint4*)(qvb + (size_t)sA * 512 + cl * 16);
        uint4 uB = *(const uint4*)(qvb + (size_t)sB * 512 + cl * 16);
        EDGE4(uA);
        EDGE4(uB);
    }
    if (j < s1) {
        int sA = esrc[j];
        uint4 uA = *(const uint4*)(qvb + (size_t)sA * 512 + cl * 16);
        EDGE4(uA);
    }
#undef EDGE4

    a0 += __shfl_xor(a0, 32);
    a1 += __shfl_xor(a1, 32);
    a2 += __shfl_xor(a2, 32);
    a3 += __shfl_xor(a3, 32);
    if (half == 0) {
        float4* sp = (float4*)(S + (size_t)d * HDIM) + cl;
        float4 o = *sp;
        o.x += a0; o.y += a1; o.z += a2; o.w += a3;
        *sp = o;
    }
}

// ---------------------------------------------------------------------------
// stats: per-channel sum / sumsq of S
// ---------------------------------------------------------------------------
__global__ void stats_kernel(const float* __restrict__ s,
                             float* __restrict__ stats, int n) {
    int c = threadIdx.x & 127, rh = threadIdx.x >> 7;
    int r0 = blockIdx.x * 128;
    int r1 = min(r0 + 128, n);
    float sum = 0.f, sq = 0.f;
    for (int r = r0 + rh; r < r1; r += 2) {
        float v = s[(size_t)r * HDIM + c];
        sum += v;
        sq = fmaf(v, v, sq);
    }
    __shared__ float ls[2][HDIM], lq[2][HDIM];
    ls[rh][c] = sum;
    lq[rh][c] = sq;
    __syncthreads();
    if (rh == 0) {
        atomicAdd(&stats[c], ls[0][c] + ls[1][c]);
        atomicAdd(&stats[HDIM + c], lq[0][c] + lq[1][c]);
    }
}

// ---------------------------------------------------------------------------
// head_bn: out = relu(bn(S)) @ head_w + head_b
// ---------------------------------------------------------------------------
__global__ void head_bn_kernel(const float* __restrict__ S,
                               const float* __restrict__ stats,
                               const float* __restrict__ gamma,
                               const float* __restrict__ beta,
                               const float* __restrict__ w,
                               const float* __restrict__ b,
                               float* __restrict__ out, int n) {
    __shared__ float hsm[8][HDIM];
    float invn = 1.f / (float)n;
    for (int i = threadIdx.x; i < 8 * HDIM; i += 256) {
        int r = i >> 7, c = i & 127;
        int node = blockIdx.x * 8 + r;
        float v = 0.f;
        if (node < n) {
            float mean = stats[c] * invn;
            float var = stats[128 + c] * invn - mean * mean;
            float sc = gamma[c] * rsqrtf(var + BN_EPS);
            float sh = beta[c] - mean * sc;
            v = fmaxf(fmaf(S[(size_t)node * HDIM + c], sc, sh), 0.f);
        }
        hsm[r][c] = v;
    }
    __syncthreads();
    int c = threadIdx.x & 31;
    int ng = threadIdx.x >> 5;
    int node = blockIdx.x * 8 + ng;
    if (node >= n) return;
    float acc = b[c];
#pragma unroll
    for (int k = 0; k < HDIM; ++k)
        acc = fmaf(hsm[ng][k], w[k * OCDIM + c], acc);
    out[(size_t)node * OCDIM + c] = acc;
}

// ---------------------------------------------------------------------------
extern "C" void kernel_launch(void* const* d_in, const int* in_sizes, int n_in,
                              void* d_out, int out_size, void* d_ws, size_t ws_size,
                              hipStream_t stream) {
    const float* x      = (const float*)d_in[0];
    const int*   ei     = (const int*)  d_in[1];
    const float* proj_w = (const float*)d_in[2];
    const float* proj_b = (const float*)d_in[3];
    const float* conv_w = (const float*)d_in[4];  // [3][4][128][128]
    const float* conv_b = (const float*)d_in[5];  // [3][4][128]
    const float* bn_g   = (const float*)d_in[6];
    const float* bn_b   = (const float*)d_in[7];
    const float* head_w = (const float*)d_in[8];
    const float* head_b = (const float*)d_in[9];
    float* out = (float*)d_out;

    int n = in_sizes[0] / ICDIM;   // 50000
    int e = in_sizes[1] / 2;       // 600000

    size_t nh = (size_t)n * HDIM;
    // S f32 | st[768] | h bf16 | K bf16 | QV u32 | Wt | Wp | ints
    size_t need = nh * 4 + 768 * 4 + nh * 2 + nh * 2 + nh * 4
                + (size_t)12 * HDIM * HDIM * 2 + (size_t)HDIM * ICDIM * 2
                + ((size_t)3 * n + (n + 1) + 256 + e) * 4;
    if (ws_size < need) return;

    float* S  = (float*)d_ws;
    float* st = S + nh;                         // 3 x (sum[128], sumsq[128])
    __hip_bfloat16* h = (__hip_bfloat16*)(st + 768);
    __hip_bfloat16* K = h + nh;
    unsigned int* QV = (unsigned int*)(K + nh); // [n][128] words (8B interleave)
    __hip_bfloat16* Wt = (__hip_bfloat16*)(QV + nh);     // [3][4][128o][128i]
    __hip_bfloat16* Wp = Wt + (size_t)12 * HDIM * HDIM;  // [128o][64i]

    int* deg    = (int*)(Wp + (size_t)HDIM * ICDIM);
    int* incl   = deg + n;
    int* off    = incl + n;                     // n+1
    int* cursor = off + n + 1;
    int* bsum   = cursor + n;                   // 256
    int* esrc   = bsum + 256;                   // e

    hipMemsetAsync(st, 0, 768 * sizeof(float), stream);
    hipMemsetAsync(deg, 0, (size_t)n * sizeof(int), stream);

    int gb_e = (e + 255) / 256;
    int gb_n = (n + 255) / 256;   // 196 <= 256

    wprep_kernel<<<13, 256, 0, stream>>>(conv_w, proj_w, Wt, Wp);
    proj_mfma_kernel<<<(n + NCH - 1) / NCH, 256, 0, stream>>>(x, Wp, proj_b, h, n);

    hist_kernel<<<gb_e, 256, 0, stream>>>(ei, deg, e);
    scan1_kernel<<<gb_n, 256, 0, stream>>>(deg, incl, bsum, n);
    scan23_kernel<<<gb_n, 256, 0, stream>>>(deg, incl, bsum, off, cursor, n, e, gb_n);
    scatter_kernel<<<gb_e, 256, 0, stream>>>(ei, cursor, esrc, e);

    int gm = (n + NCHG - 1) / NCHG;
    for (int l = 0; l < 3; ++l) {
        const float* Ssrc = (l == 0) ? nullptr : S;
        const float* stp  = (l == 0) ? st : st + (size_t)(l - 1) * 256;
        const float* gma  = (l == 0) ? bn_g : bn_g + (size_t)(l - 1) * HDIM;
        const float* bta  = (l == 0) ? bn_b : bn_b + (size_t)(l - 1) * HDIM;
        gemm4_fused_kernel<<<gm, 1024, 0, stream>>>(
            h, Ssrc, stp, gma, bta,
            Wt + (size_t)l * 4 * HDIM * HDIM, conv_b + (size_t)l * 4 * HDIM,
            K, QV, S, n);
        agg_kernel<<<(n + 3) / 4, 256, 0, stream>>>(off, esrc, K, QV, S, n);
        stats_kernel<<<(n + 127) / 128, 256, 0, stream>>>(S, st + l * 256, n);
    }

    head_bn_kernel<<<(n + 7) / 8, 256, 0, stream>>>(
        S, st + 2 * 256, bn_g + 2 * HDIM, bn_b + 2 * HDIM, head_w, head_b, out, n);
}

// Round 14
// 445.666 us; speedup vs baseline: 1.1057x; 1.0453x over previous
//
#include <hip/hip_runtime.h>
#include <hip/hip_bf16.h>
#include <math.h>

#define HDIM 128
#define ICDIM 64
#define OCDIM 32
#define BN_EPS 1e-5f
#define NCH 64    // nodes per proj block
#define NCHG 128  // nodes per gemm4 block

typedef __attribute__((ext_vector_type(8))) short bv8;   // 8 x bf16 bits (4 VGPR)
typedef __attribute__((ext_vector_type(4))) float fv4;   // MFMA accumulator

static __device__ __forceinline__ unsigned short f2bf(float v) {
    __hip_bfloat16 t = __float2bfloat16(v);
    return *(unsigned short*)&t;
}
static __device__ __forceinline__ float bflo(unsigned int u) {
    union { unsigned int i; float f; } c; c.i = u << 16; return c.f;
}
static __device__ __forceinline__ float bfhi(unsigned int u) {
    union { unsigned int i; float f; } c; c.i = u & 0xffff0000u; return c.f;
}
static __device__ __forceinline__ unsigned int pack2bf(float a, float b) {
    return (unsigned int)f2bf(a) | ((unsigned int)f2bf(b) << 16);
}

// ---------------------------------------------------------------------------
// wprep: blocks 0..11: conv_w -> Wt [12][128o][128i] bf16; block 12: proj_w -> Wp
// ---------------------------------------------------------------------------
__global__ void wprep_kernel(const float* __restrict__ conv_w,
                             const float* __restrict__ proj_w,
                             __hip_bfloat16* __restrict__ Wt,
                             __hip_bfloat16* __restrict__ Wp) {
    int mat = blockIdx.x;
    if (mat < 12) {
        const float* s = conv_w + (size_t)mat * HDIM * HDIM;
        __hip_bfloat16* d = Wt + (size_t)mat * HDIM * HDIM;
        for (int idx = threadIdx.x; idx < HDIM * HDIM; idx += 256) {
            int i = idx >> 7, o = idx & 127;
            d[(size_t)o * HDIM + i] = __float2bfloat16(s[idx]);
        }
    } else {
        for (int idx = threadIdx.x; idx < ICDIM * HDIM; idx += 256) {
            int i = idx >> 7, o = idx & 127;
            Wp[(size_t)o * ICDIM + i] = __float2bfloat16(proj_w[idx]);
        }
    }
}

// ---------------------------------------------------------------------------
// proj_mfma: h = relu(x @ proj_w + proj_b) -> bf16 h   (xs XOR-swizzled)
// ---------------------------------------------------------------------------
__global__ __launch_bounds__(256)
void proj_mfma_kernel(const float* __restrict__ x,
                      const __hip_bfloat16* __restrict__ wp,  // [128o][64i]
                      const float* __restrict__ b,
                      __hip_bfloat16* __restrict__ h, int n) {
    __shared__ unsigned int xs[NCH * ICDIM / 2];   // 8 KB bf16, [node][64] swizzled
    int tid = threadIdx.x;
    int m0 = blockIdx.x * NCH;

    const float2* xsrc = (const float2*)(x + (size_t)m0 * ICDIM);
    for (int i = tid; i < NCH * ICDIM / 2; i += 256) {
        int node = m0 + (i >> 5);
        float2 v = (node < n) ? xsrc[i] : (float2){0.f, 0.f};
        xs[i ^ (((i >> 5) & 7) << 2)] = pack2bf(v.x, v.y);   // word-level swizzle
    }

    int wv = tid >> 6;          // 0..3  -> out-ch slice wv*32
    int lane = tid & 63;
    int j = lane & 15;          // node-in-tile
    int kg = lane >> 4;         // k-group
    int sw = (j & 7) << 4;      // read-side swizzle (row&7 == j&7)

    bv8 af[2][2];
#pragma unroll
    for (int gs = 0; gs < 2; ++gs)
#pragma unroll
        for (int ks = 0; ks < 2; ++ks)
            af[gs][ks] = *(const bv8*)((const unsigned short*)wp +
                (size_t)(wv * 32 + gs * 16 + j) * ICDIM + ks * 32 + kg * 8);

    float4 bias0 = *(const float4*)(b + wv * 32 + kg * 4);
    float4 bias1 = *(const float4*)(b + wv * 32 + 16 + kg * 4);

    __syncthreads();

#pragma unroll
    for (int t4 = 0; t4 < NCH / 16; ++t4) {
        const char* rowbase = (const char*)xs + (t4 * 16 + j) * (ICDIM * 2);
        fv4 acc0 = (fv4){0.f, 0.f, 0.f, 0.f};
        fv4 acc1 = (fv4){0.f, 0.f, 0.f, 0.f};
#pragma unroll
        for (int ks = 0; ks < 2; ++ks) {
            bv8 bf = *(const bv8*)(rowbase + ((kg * 16 + ks * 64) ^ sw));
            acc0 = __builtin_amdgcn_mfma_f32_16x16x32_bf16(af[0][ks], bf, acc0, 0, 0, 0);
            acc1 = __builtin_amdgcn_mfma_f32_16x16x32_bf16(af[1][ks], bf, acc1, 0, 0, 0);
        }
        int node = m0 + t4 * 16 + j;
        if (node < n) {
            unsigned short* o =
                (unsigned short*)h + (size_t)node * HDIM + wv * 32 + kg * 4;
            ushort4 r0, r1;
            r0.x = f2bf(fmaxf(acc0.x + bias0.x, 0.f));
            r0.y = f2bf(fmaxf(acc0.y + bias0.y, 0.f));
            r0.z = f2bf(fmaxf(acc0.z + bias0.z, 0.f));
            r0.w = f2bf(fmaxf(acc0.w + bias0.w, 0.f));
            r1.x = f2bf(fmaxf(acc1.x + bias1.x, 0.f));
            r1.y = f2bf(fmaxf(acc1.y + bias1.y, 0.f));
            r1.z = f2bf(fmaxf(acc1.z + bias1.z, 0.f));
            r1.w = f2bf(fmaxf(acc1.w + bias1.w, 0.f));
            *(ushort4*)o = r0;
            *(ushort4*)(o + 16) = r1;
        }
    }
}

// ---------------------------------------------------------------------------
// gemm4_fused: one block = 128 nodes x all 4 lins; 16 waves = 4 lins x 4 slices.
//   hs XOR-swizzled; weights in registers.  S is bf16 now (f32 math in regs).
//   Layer 0 stages from h; layers 1,2 stage bn(relu(S_bf16)) inline.
// ---------------------------------------------------------------------------
__global__ __launch_bounds__(1024)
void gemm4_fused_kernel(const __hip_bfloat16* __restrict__ hB,
                        const __hip_bfloat16* __restrict__ Ssrc, // null for layer 0
                        const float* __restrict__ stp,        // stats prev layer
                        const float* __restrict__ gma,
                        const float* __restrict__ bta,
                        const __hip_bfloat16* __restrict__ wt4, // [4][128o][128i]
                        const float* __restrict__ b4,           // [4][128]
                        __hip_bfloat16* __restrict__ K,
                        unsigned int* __restrict__ QV,          // [n][128] words
                        __hip_bfloat16* __restrict__ S, int n) {
    __shared__ unsigned short hs[NCHG * HDIM];   // 32 KB, swizzled
    int tid = threadIdx.x;
    int m0 = blockIdx.x * NCHG;

    if (Ssrc) {
        // stage 128 x 128 bf16 -> bn+relu -> bf16 LDS; uint4 = 8 channels
        const uint4* src = (const uint4*)Ssrc;
        float invn = 1.f / (float)n;
#pragma unroll
        for (int it = 0; it < 2; ++it) {
            int idx = it * 1024 + tid;                    // granule 0..2047
            uint4 u = src[(size_t)blockIdx.x * 2048 + idx];
            int c0 = (idx * 8) & 127;
            float vv[8] = {bflo(u.x), bfhi(u.x), bflo(u.y), bfhi(u.y),
                           bflo(u.z), bfhi(u.z), bflo(u.w), bfhi(u.w)};
            int wsw = ((idx >> 4) & 7) << 4;
            unsigned int* dst = (unsigned int*)((char*)hs + ((idx * 16) ^ wsw));
#pragma unroll
            for (int p = 0; p < 8; p += 2) {
                int c = c0 + p;
                float mA = stp[c] * invn, mB = stp[c + 1] * invn;
                float scA = gma[c] * rsqrtf(stp[128 + c] * invn - mA * mA + BN_EPS);
                float scB = gma[c + 1] * rsqrtf(stp[129 + c] * invn - mB * mB + BN_EPS);
                float shA = bta[c] - mA * scA, shB = bta[c + 1] - mB * scB;
                float rA = fmaxf(fmaf(vv[p], scA, shA), 0.f);
                float rB = fmaxf(fmaf(vv[p + 1], scB, shB), 0.f);
                dst[p >> 1] = pack2bf(rA, rB);
            }
        }
    } else {
        const uint4* src = (const uint4*)((const unsigned short*)hB + (size_t)m0 * HDIM);
#pragma unroll
        for (int it = 0; it < 2; ++it) {
            int idx = it * 1024 + tid;
            int wsw = ((idx >> 4) & 7) << 4;
            *(uint4*)((char*)hs + ((idx * 16) ^ wsw)) = src[idx];
        }
    }

    int wv = tid >> 6;          // 0..15
    int lane = tid & 63;
    int lin = wv >> 2;          // 0..3
    int g2 = wv & 3;            // out-channel slice: channels g2*32 .. +31
    int j = lane & 15;          // node-in-tile (B col, D col)
    int kg = lane >> 4;         // k-group
    int sw = (j & 7) << 4;      // read-side swizzle (row&7 == j&7)

    const unsigned short* wbase =
        (const unsigned short*)(wt4 + (size_t)lin * HDIM * HDIM);
    bv8 af[2][4];
#pragma unroll
    for (int gs = 0; gs < 2; ++gs)
#pragma unroll
        for (int ks = 0; ks < 4; ++ks)
            af[gs][ks] = *(const bv8*)(wbase +
                (size_t)(g2 * 32 + gs * 16 + j) * HDIM + ks * 32 + kg * 8);

    const float* bl = b4 + lin * HDIM;
    float4 bias0 = *(const float4*)(bl + g2 * 32 + kg * 4);
    float4 bias1 = *(const float4*)(bl + g2 * 32 + 16 + kg * 4);

    __syncthreads();

#pragma unroll
    for (int t4 = 0; t4 < NCHG / 16; ++t4) {
        const char* rowbase = (const char*)hs + (t4 * 16 + j) * (HDIM * 2);
        fv4 acc0 = (fv4){0.f, 0.f, 0.f, 0.f};
        fv4 acc1 = (fv4){0.f, 0.f, 0.f, 0.f};
#pragma unroll
        for (int ks = 0; ks < 4; ++ks) {
            bv8 bf = *(const bv8*)(rowbase + ((kg * 16 + ks * 64) ^ sw));
            acc0 = __builtin_amdgcn_mfma_f32_16x16x32_bf16(af[0][ks], bf, acc0, 0, 0, 0);
            acc1 = __builtin_amdgcn_mfma_f32_16x16x32_bf16(af[1][ks], bf, acc1, 0, 0, 0);
        }
        int node = m0 + t4 * 16 + j;
        if (node >= n) continue;
        int c0 = g2 * 32 + kg * 4;
        float f0 = acc0.x + bias0.x, f1 = acc0.y + bias0.y;
        float f2 = acc0.z + bias0.z, f3 = acc0.w + bias0.w;
        float f4 = acc1.x + bias1.x, f5 = acc1.y + bias1.y;
        float f6 = acc1.z + bias1.z, f7 = acc1.w + bias1.w;
        if (lin == 3) {
            unsigned short* o = (unsigned short*)S + (size_t)node * HDIM + c0;
            *(ushort4*)o = (ushort4){f2bf(f0), f2bf(f1), f2bf(f2), f2bf(f3)};
            *(ushort4*)(o + 16) = (ushort4){f2bf(f4), f2bf(f5), f2bf(f6), f2bf(f7)};
        } else if (lin == 0) {
            unsigned short* o = (unsigned short*)K + (size_t)node * HDIM + c0;
            *(ushort4*)o = (ushort4){f2bf(f0), f2bf(f1), f2bf(f2), f2bf(f3)};
            *(ushort4*)(o + 16) = (ushort4){f2bf(f4), f2bf(f5), f2bf(f6), f2bf(f7)};
        } else {
            // 8B-granular QV: chunk c0/4 at ushort 2*c0; q at +0, v at +4
            unsigned short* o = (unsigned short*)QV + (size_t)node * 256 + 2 * c0
                              + ((lin == 2) ? 4 : 0);
            *(ushort4*)o = (ushort4){f2bf(f0), f2bf(f1), f2bf(f2), f2bf(f3)};
            *(ushort4*)(o + 32) = (ushort4){f2bf(f4), f2bf(f5), f2bf(f6), f2bf(f7)};
        }
    }
}

// ---------------------------------------------------------------------------
// counting sort of edges by dst: hist -> scan1 -> scan23 -> scatter
// ---------------------------------------------------------------------------
__global__ void hist_kernel(const int* __restrict__ ei, int* __restrict__ deg, int e) {
    int i = blockIdx.x * 256 + threadIdx.x;
    if (i < e) atomicAdd(&deg[ei[(size_t)e + i]], 1);
}

__global__ void scan1_kernel(const int* __restrict__ deg, int* __restrict__ incl,
                             int* __restrict__ bsum, int n) {
    __shared__ int tmp[256];
    int i = blockIdx.x * 256 + threadIdx.x;
    int v = (i < n) ? deg[i] : 0;
    tmp[threadIdx.x] = v;
    __syncthreads();
    for (int ofs = 1; ofs < 256; ofs <<= 1) {
        int t = (threadIdx.x >= ofs) ? tmp[threadIdx.x - ofs] : 0;
        __syncthreads();
        tmp[threadIdx.x] += t;
        __syncthreads();
    }
    if (i < n) incl[i] = tmp[threadIdx.x];
    if (threadIdx.x == 255) bsum[blockIdx.x] = tmp[255];
}

__global__ void scan23_kernel(const int* __restrict__ deg, const int* __restrict__ incl,
                              const int* __restrict__ bsum, int* __restrict__ off,
                              int* __restrict__ cursor, int n, int e, int nb) {
    __shared__ int tmp[256];
    int t = threadIdx.x;
    tmp[t] = (t < nb) ? bsum[t] : 0;
    __syncthreads();
    for (int ofs = 1; ofs < 256; ofs <<= 1) {
        int a = (t >= ofs) ? tmp[t - ofs] : 0;
        __syncthreads();
        tmp[t] += a;
        __syncthreads();
    }
    int pre = (blockIdx.x == 0) ? 0 : tmp[blockIdx.x - 1];
    int i = blockIdx.x * 256 + t;
    if (i < n) {
        int ex = incl[i] - deg[i] + pre;
        off[i] = ex;
        cursor[i] = ex;
        if (i == n - 1) off[n] = e;
    }
}

__global__ void scatter_kernel(const int* __restrict__ ei, int* __restrict__ cursor,
                               int* __restrict__ esrc, int e) {
    int i = blockIdx.x * 256 + threadIdx.x;
    if (i < e) {
        int dst = ei[(size_t)e + i];
        int pos = atomicAdd(&cursor[dst], 1);
        esrc[pos] = ei[i];
    }
}

// ---------------------------------------------------------------------------
// agg: S[d] += sum_{j in seg(d)} sigmoid(k[d] + q[src_j]) * v[src_j]
// one wave per dst; uint4 gather serves 2 edges; S RMW in bf16.
// ---------------------------------------------------------------------------
__global__ void agg_kernel(const int* __restrict__ off, const int* __restrict__ esrc,
                           const __hip_bfloat16* __restrict__ kb,
                           const unsigned int* __restrict__ QV,
                           __hip_bfloat16* __restrict__ S, int n) {
    int d = blockIdx.x * 4 + (threadIdx.x >> 6);
    if (d >= n) return;
    int lane = threadIdx.x & 63;
    int half = lane >> 5;       // edge parity within the pair
    int cl = lane & 31;         // 4-channel chunk index
    const char* qvb = (const char*)QV;

    uint2 ku = *(const uint2*)((const unsigned short*)kb + (size_t)d * HDIM + 4 * cl);
    float k0 = bflo(ku.x), k1 = bfhi(ku.x), k2 = bflo(ku.y), k3 = bfhi(ku.y);
    float a0 = 0.f, a1 = 0.f, a2 = 0.f, a3 = 0.f;

#define EDGE4(u)                                                     \
    {                                                                \
        float g0 = k0 + bflo(u.x), g1 = k1 + bfhi(u.x);              \
        float g2 = k2 + bflo(u.y), g3 = k3 + bfhi(u.y);              \
        a0 += __fdividef(bflo(u.z), 1.f + __expf(-g0));              \
        a1 += __fdividef(bfhi(u.z), 1.f + __expf(-g1));              \
        a2 += __fdividef(bflo(u.w), 1.f + __expf(-g2));              \
        a3 += __fdividef(bfhi(u.w), 1.f + __expf(-g3));              \
    }

    int j = off[d] + half, s1 = off[d + 1];
    for (; j + 2 < s1; j += 4) {
        int sA = esrc[j], sB = esrc[j + 2];
        uint4 uA = *(const uint4*)(qvb + (size_t)sA * 512 + cl * 16);
        uint4 uB = *(const uint4*)(qvb + (size_t)sB * 512 + cl * 16);
        EDGE4(uA);
        EDGE4(uB);
    }
    if (j < s1) {
        int sA = esrc[j];
        uint4 uA = *(const uint4*)(qvb + (size_t)sA * 512 + cl * 16);
        EDGE4(uA);
    }
#undef EDGE4

    a0 += __shfl_xor(a0, 32);
    a1 += __shfl_xor(a1, 32);
    a2 += __shfl_xor(a2, 32);
    a3 += __shfl_xor(a3, 32);
    if (half == 0) {
        unsigned int* sp = (unsigned int*)S + (size_t)d * 64 + 2 * cl;
        uint2 o = *(uint2*)sp;
        float b0 = bflo(o.x) + a0, b1 = bfhi(o.x) + a1;
        float b2 = bflo(o.y) + a2, b3 = bfhi(o.y) + a3;
        uint2 w2;
        w2.x = pack2bf(b0, b1);
        w2.y = pack2bf(b2, b3);
        *(uint2*)sp = w2;
    }
}

// ---------------------------------------------------------------------------
// stats: per-channel sum / sumsq of bf16 S (vectorized uint reads)
// ---------------------------------------------------------------------------
__global__ void stats_kernel(const __hip_bfloat16* __restrict__ s,
                             float* __restrict__ stats, int n) {
    int c2 = threadIdx.x & 63;   // word index (channels 2c2, 2c2+1)
    int rh = threadIdx.x >> 6;   // 0..3
    int r0 = blockIdx.x * 128;
    int r1 = min(r0 + 128, n);
    const unsigned int* sw = (const unsigned int*)s;
    float s0 = 0.f, s1 = 0.f, q0 = 0.f, q1 = 0.f;
    for (int r = r0 + rh; r < r1; r += 4) {
        unsigned int u = sw[(size_t)r * 64 + c2];
        float a = bflo(u), b = bfhi(u);
        s0 += a; q0 = fmaf(a, a, q0);
        s1 += b; q1 = fmaf(b, b, q1);
    }
    __shared__ float ls[4][128], lq[4][128];
    ls[rh][2 * c2] = s0; ls[rh][2 * c2 + 1] = s1;
    lq[rh][2 * c2] = q0; lq[rh][2 * c2 + 1] = q1;
    __syncthreads();
    int t = threadIdx.x;
    if (t < 128) {
        atomicAdd(&stats[t], ls[0][t] + ls[1][t] + ls[2][t] + ls[3][t]);
    } else {
        int c = t - 128;
        atomicAdd(&stats[128 + c], lq[0][c] + lq[1][c] + lq[2][c] + lq[3][c]);
    }
}

// ---------------------------------------------------------------------------
// head_bn: out = relu(bn(S_bf16)) @ head_w + head_b
// ---------------------------------------------------------------------------
__global__ void head_bn_kernel(const __hip_bfloat16* __restrict__ S,
                               const float* __restrict__ stats,
                               const float* __restrict__ gamma,
                               const float* __restrict__ beta,
                               const float* __restrict__ w,
                               const float* __restrict__ b,
                               float* __restrict__ out, int n) {
    __shared__ float hsm[8][HDIM];
    float invn = 1.f / (float)n;
    const unsigned int* sw = (const unsigned int*)S;
    for (int wd = threadIdx.x; wd < 8 * 64; wd += 256) {
        int r = wd >> 6, c2 = wd & 63;
        int node = blockIdx.x * 8 + r;
        float v0 = 0.f, v1 = 0.f;
        if (node < n) {
            unsigned int u = sw[(size_t)node * 64 + c2];
            int c = 2 * c2;
            float m0 = stats[c] * invn;
            float var0 = stats[128 + c] * invn - m0 * m0;
            float sc0 = gamma[c] * rsqrtf(var0 + BN_EPS);
            float sh0 = beta[c] - m0 * sc0;
            v0 = fmaxf(fmaf(bflo(u), sc0, sh0), 0.f);
            float m1 = stats[c + 1] * invn;
            float var1 = stats[129 + c] * invn - m1 * m1;
            float sc1 = gamma[c + 1] * rsqrtf(var1 + BN_EPS);
            float sh1 = beta[c + 1] - m1 * sc1;
            v1 = fmaxf(fmaf(bfhi(u), sc1, sh1), 0.f);
        }
        hsm[r][2 * c2] = v0;
        hsm[r][2 * c2 + 1] = v1;
    }
    __syncthreads();
    int c = threadIdx.x & 31;
    int ng = threadIdx.x >> 5;
    int node = blockIdx.x * 8 + ng;
    if (node >= n) return;
    float acc = b[c];
#pragma unroll
    for (int k = 0; k < HDIM; ++k)
        acc = fmaf(hsm[ng][k], w[k * OCDIM + c], acc);
    out[(size_t)node * OCDIM + c] = acc;
}

// ---------------------------------------------------------------------------
extern "C" void kernel_launch(void* const* d_in, const int* in_sizes, int n_in,
                              void* d_out, int out_size, void* d_ws, size_t ws_size,
                              hipStream_t stream) {
    const float* x      = (const float*)d_in[0];
    const int*   ei     = (const int*)  d_in[1];
    const float* proj_w = (const float*)d_in[2];
    const float* proj_b = (const float*)d_in[3];
    const float* conv_w = (const float*)d_in[4];  // [3][4][128][128]
    const float* conv_b = (const float*)d_in[5];  // [3][4][128]
    const float* bn_g   = (const float*)d_in[6];
    const float* bn_b   = (const float*)d_in[7];
    const float* head_w = (const float*)d_in[8];
    const float* head_b = (const float*)d_in[9];
    float* out = (float*)d_out;

    int n = in_sizes[0] / ICDIM;   // 50000
    int e = in_sizes[1] / 2;       // 600000

    size_t nh = (size_t)n * HDIM;
    // S bf16 | st f32[768] | h bf16 | K bf16 | QV u32 | Wt | Wp | ints
    size_t need = nh * 2 + 768 * 4 + nh * 2 + nh * 2 + nh * 4
                + (size_t)12 * HDIM * HDIM * 2 + (size_t)HDIM * ICDIM * 2
                + ((size_t)3 * n + (n + 1) + 256 + e) * 4;
    if (ws_size < need) return;

    __hip_bfloat16* S = (__hip_bfloat16*)d_ws;
    float* st = (float*)(S + nh);               // 3 x (sum[128], sumsq[128])
    __hip_bfloat16* h = (__hip_bfloat16*)(st + 768);
    __hip_bfloat16* K = h + nh;
    unsigned int* QV = (unsigned int*)(K + nh); // [n][128] words (8B interleave)
    __hip_bfloat16* Wt = (__hip_bfloat16*)(QV + nh);     // [3][4][128o][128i]
    __hip_bfloat16* Wp = Wt + (size_t)12 * HDIM * HDIM;  // [128o][64i]

    int* deg    = (int*)(Wp + (size_t)HDIM * ICDIM);
    int* incl   = deg + n;
    int* off    = incl + n;                     // n+1
    int* cursor = off + n + 1;
    int* bsum   = cursor + n;                   // 256
    int* esrc   = bsum + 256;                   // e

    hipMemsetAsync(st, 0, 768 * sizeof(float), stream);
    hipMemsetAsync(deg, 0, (size_t)n * sizeof(int), stream);

    int gb_e = (e + 255) / 256;
    int gb_n = (n + 255) / 256;   // 196 <= 256

    wprep_kernel<<<13, 256, 0, stream>>>(conv_w, proj_w, Wt, Wp);
    proj_mfma_kernel<<<(n + NCH - 1) / NCH, 256, 0, stream>>>(x, Wp, proj_b, h, n);

    hist_kernel<<<gb_e, 256, 0, stream>>>(ei, deg, e);
    scan1_kernel<<<gb_n, 256, 0, stream>>>(deg, incl, bsum, n);
    scan23_kernel<<<gb_n, 256, 0, stream>>>(deg, incl, bsum, off, cursor, n, e, gb_n);
    scatter_kernel<<<gb_e, 256, 0, stream>>>(ei, cursor, esrc, e);

    int gm = (n + NCHG - 1) / NCHG;
    for (int l = 0; l < 3; ++l) {
        const __hip_bfloat16* Ssrc = (l == 0) ? nullptr : S;
        const float* stp  = (l == 0) ? st : st + (size_t)(l - 1) * 256;
        const float* gma  = (l == 0) ? bn_g : bn_g + (size_t)(l - 1) * HDIM;
        const float* bta  = (l == 0) ? bn_b : bn_b + (size_t)(l - 1) * HDIM;
        gemm4_fused_kernel<<<gm, 1024, 0, stream>>>(
            h, Ssrc, stp, gma, bta,
            Wt + (size_t)l * 4 * HDIM * HDIM, conv_b + (size_t)l * 4 * HDIM,
            K, QV, S, n);
        agg_kernel<<<(n + 3) / 4, 256, 0, stream>>>(off, esrc, K, QV, S, n);
        stats_kernel<<<(n + 127) / 128, 256, 0, stream>>>(S, st + l * 256, n);
    }

    head_bn_kernel<<<(n + 7) / 8, 256, 0, stream>>>(
        S, st + 2 * 256, bn_g + 2 * HDIM, bn_b + 2 * HDIM, head_w, head_b, out, n);
}